// Round 9
// baseline (474.238 us; speedup 1.0000x reference)
//
#include <hip/hip_runtime.h>
#include <hip/hip_fp16.h>
#include <math.h>
#include <stdint.h>

#define B_ 32
#define S_ 2048
#define H_ 1024

typedef _Float16 f16;
typedef _Float16 f16x8 __attribute__((ext_vector_type(8)));
typedef _Float16 f16x4 __attribute__((ext_vector_type(4)));
typedef float    f32x4 __attribute__((ext_vector_type(4)));

// ---------------- k0: W_c fp32 -> fp16 row-major (fallback only) ----------
__global__ void k_cvt_wc(const float* __restrict__ wc, f16* __restrict__ wc16) {
    int i = (blockIdx.x * 256 + threadIdx.x) * 4;
    float4 vv = *(const float4*)(wc + i);
    f16x4 h;
    h[0] = (f16)vv.x; h[1] = (f16)vv.y; h[2] = (f16)vv.z; h[3] = (f16)vv.w;
    *(f16x4*)(wc16 + i) = h;
}

// ---------------- k0b: fp32 -> fp16 pre-swizzled 32KB images --------------
// image (rt, kc 0..15): rows r=0..255 (128B/row), k=0..63.
// byte(r,k) = r*128 + (((k>>3)*16) ^ ((r&7)<<4)) + (k&7)*2
// Fast path: used for Wc only (rt 0..3, grid 64). enc images are produced
// as a side-product of k_gemm.
__global__ void k_cvt_img(const float* __restrict__ src, f16* __restrict__ dst) {
    int bid = blockIdx.x;                 // rt*16 + kc
    int rt = bid >> 4, kc = bid & 15;
    int tid = threadIdx.x;
    char* img = (char*)dst + ((size_t)bid << 15);
    #pragma unroll
    for (int i = 0; i < 8; ++i) {
        int gid = i * 256 + tid;          // 0..2047
        int r = gid >> 3, kg = gid & 7;
        const float* s = src + ((size_t)(rt * 256 + r)) * H_ + kc * 64 + kg * 8;
        float4 lo = *(const float4*)s;
        float4 hi = *(const float4*)(s + 4);
        f16x8 h;
        h[0]=(f16)lo.x; h[1]=(f16)lo.y; h[2]=(f16)lo.z; h[3]=(f16)lo.w;
        h[4]=(f16)hi.x; h[5]=(f16)hi.y; h[6]=(f16)hi.z; h[7]=(f16)hi.w;
        int byte = r * 128 + ((kg * 16) ^ ((r & 7) << 4));
        *(f16x8*)(img + byte) = h;
    }
}

// ---------------- k1: hidden_proj = hidden @ W_h.T + b_h ----------------
__global__ void k_hp(const float* __restrict__ hid, const float* __restrict__ Wh,
                     const float* __restrict__ bh, float* __restrict__ hp) {
    int wid  = (blockIdx.x * 256 + threadIdx.x) >> 6;
    int lane = threadIdx.x & 63;
    int b = wid >> 10, oo = wid & 1023;
    const float* hrow = hid + b * H_;
    const float* wrow = Wh + (size_t)oo * H_;
    float s = 0.f;
    #pragma unroll
    for (int i = 0; i < 16; ++i) {
        int k = i * 64 + lane;
        s += hrow[k] * wrow[k];
    }
    #pragma unroll
    for (int m = 32; m; m >>= 1) s += __shfl_xor(s, m);
    if (lane == 0) hp[wid] = s + bh[oo];
}

// ---------------- k2: 256x256 tile, fused fp32-A cvt + image side-write ---
// r5 structure (one syncthreads/tile, 24 ds_read + 64 MFMA) but A comes from
// fp32 enc: reg-stage 8xfloat4/thread issued one full tile early (T14),
// cvt to f16 (RTE, bit-identical to cvt_img), ds_write the same swizzled
// image bytes into LDS, and store the i==nt quarter to enc16 for k_ctxpart16.
// Eliminates the 61 us enc cvt pass. B still gload_lds from wc16 images.
#define GLD(dst_, src_) __builtin_amdgcn_global_load_lds(                      \
    (const __attribute__((address_space(1))) uint32_t*)(src_),                 \
    (__attribute__((address_space(3))) uint32_t*)(dst_), 16, 0, 0)

#define STAGE_B(t_) do {                                                       \
    _Pragma("unroll")                                                          \
    for (int i_ = 0; i_ < 4; ++i_) {                                           \
        int off_ = (i_ * 512 + tid) * 16;                                      \
        GLD(&Als[(t_) & 1][32768 + off_], bimg + ((size_t)(t_) << 15) + off_); \
    }                                                                          \
} while (0)

// load fp32 A for tile t_ into register set S_
#define LDA(t_, S_) do {                                                       \
    _Pragma("unroll")                                                          \
    for (int i_ = 0; i_ < 4; ++i_) {                                           \
        const float* s_ = asrc + (size_t)(i_ * 64) * H_ + (t_) * 64;           \
        S_[i_][0] = *(const float4*)s_;                                        \
        S_[i_][1] = *(const float4*)(s_ + 4);                                  \
    }                                                                          \
} while (0)

// cvt S_ -> f16 image bytes; write LDS A-region of buf[t_&1]; store quarter
#define WRA(t_, S_) do {                                                       \
    _Pragma("unroll")                                                          \
    for (int i_ = 0; i_ < 4; ++i_) {                                           \
        f16x8 h_;                                                              \
        h_[0]=(f16)S_[i_][0].x; h_[1]=(f16)S_[i_][0].y;                        \
        h_[2]=(f16)S_[i_][0].z; h_[3]=(f16)S_[i_][0].w;                        \
        h_[4]=(f16)S_[i_][1].x; h_[5]=(f16)S_[i_][1].y;                        \
        h_[6]=(f16)S_[i_][1].z; h_[7]=(f16)S_[i_][1].w;                        \
        int off_ = (i_ * 512 + tid) * 16;                                      \
        *(f16x8*)(&Als[(t_) & 1][off_]) = h_;                                  \
        if (i_ == nt)                                                          \
            *(f16x8*)(aimg16 + ((size_t)(t_) << 15) + off_) = h_;              \
    }                                                                          \
} while (0)

#define COMP(kc_) do {                                                         \
    const char* buf_ = Als[(kc_) & 1];                                         \
    _Pragma("unroll")                                                          \
    for (int ks_ = 0; ks_ < 2; ++ks_) {                                        \
        const int coff_ = (ks_ * 64 + g * 16) ^ rsw;                           \
        f16x8 bfv_[4];                                                         \
        _Pragma("unroll")                                                      \
        for (int in_ = 0; in_ < 4; ++in_)                                      \
            bfv_[in_] = *(const f16x8*)(buf_ + 32768 + bbase[in_] + coff_);    \
        f16x8 af_[8];                                                          \
        _Pragma("unroll")                                                      \
        for (int im_ = 0; im_ < 8; ++im_)                                      \
            af_[im_] = *(const f16x8*)(buf_ + abase[im_] + coff_);             \
        _Pragma("unroll")                                                      \
        for (int im_ = 0; im_ < 8; ++im_)                                      \
            _Pragma("unroll")                                                  \
            for (int in_ = 0; in_ < 4; ++in_)                                  \
                acc[im_][in_] = __builtin_amdgcn_mfma_f32_16x16x32_f16(        \
                    af_[im_], bfv_[in_], acc[im_][in_], 0, 0, 0);              \
    }                                                                          \
} while (0)

__global__ __launch_bounds__(512, 2) void k_gemm(
        const float* __restrict__ enc, const f16* __restrict__ wc16,
        f16* __restrict__ enc16,
        const float* __restrict__ hp, const float* __restrict__ bc,
        const float* __restrict__ v, float* __restrict__ spart) {
    __shared__ __align__(16) char Als[2][65536];   // 128 KB

    const int tid = threadIdx.x;
    const int hb  = blockIdx.x;
    const int o   = (hb & 7) * 128 + (hb >> 3);    // bijective XCD swizzle
    const int mtile = o >> 2, nt = o & 3;          // 256-row / 256-col tiles
    const int brow = mtile >> 3;                   // batch
    const int lane = tid & 63, wid = tid >> 6;     // wid 0..7
    const int waveM = wid >> 2, waveN = wid & 3;
    const int g = lane >> 4, l15 = lane & 15;
    const int rsw = (l15 & 7) << 4;

    // fp32 A staging decomposition: image 16B-slot idx16 = i*512 + tid
    //   r = idx16>>3 = i*64 + (tid>>3), x = tid&7, kg = x ^ (r&7)
    const int srow = tid >> 3;
    const int skg  = (tid & 7) ^ (srow & 7);
    const float* asrc = enc + ((size_t)mtile * 256 + srow) * H_ + skg * 8;
    char* aimg16 = (char*)enc16 + ((size_t)mtile << 19);            // 16x32KB
    const char* bimg = (const char*)wc16 + ((size_t)nt << 19);      // 16x32KB

    // A frag row base bytes: row = waveM*128 + im*16 + l15 (128 B rows)
    int abase[8];
    #pragma unroll
    for (int im = 0; im < 8; ++im)
        abase[im] = (waveM * 128 + im * 16 + l15) * 128;
    // B frag base bytes (within B region): col = waveN*64 + in*16 + l15
    int bbase[4];
    #pragma unroll
    for (int in = 0; in < 4; ++in)
        bbase[in] = (waveN * 64 + in * 16 + l15) * 128;

    f32x4 acc[8][4];
    #pragma unroll
    for (int im = 0; im < 8; ++im)
        #pragma unroll
        for (int in = 0; in < 4; ++in) acc[im][in] = (f32x4){0.f, 0.f, 0.f, 0.f};

    float4 sA[4][2], sB[4][2];     // fp32 A ping-pong register sets

    // prologue: A(0)->sA, B(0) staged, A(0) written, A(1)->sB
    LDA(0, sA);
    STAGE_B(0);
    WRA(0, sA);
    LDA(1, sB);

    #pragma unroll 1
    for (int kc = 0; kc < 16; kc += 2) {
        __syncthreads();               // buf[(kc+1)&1] free; B(kc)/LDA landed
        WRA(kc + 1, sB);               // kc<=14 -> kc+1<=15 always valid
        STAGE_B(kc + 1);
        if (kc < 14) LDA(kc + 2, sA);  // full compute phase of slack
        COMP(kc);
        __syncthreads();
        if (kc + 1 < 15) { WRA(kc + 2, sA); STAGE_B(kc + 2); }
        if (kc + 1 < 14) LDA(kc + 3, sB);
        COMP(kc + 1);
    }

    // epilogue: partial score over this ntile's 256 cols
    float hpbcr[4], vr[4];
    #pragma unroll
    for (int in = 0; in < 4; ++in) {
        int col = nt * 256 + waveN * 64 + in * 16 + l15;
        hpbcr[in] = hp[brow * H_ + col] + bc[col];
        vr[in]    = v[col];
    }
    float* sc = (float*)Als;          // overlay Als[0]; tile 15 read Als[1]
    #pragma unroll
    for (int im = 0; im < 8; ++im) {
        #pragma unroll
        for (int r = 0; r < 4; ++r) {
            float s = 0.f;
            #pragma unroll
            for (int in = 0; in < 4; ++in) {
                float e = acc[im][in][r] + hpbcr[in];
                float ex = __expf(2.f * e);       // tanh = 1 - 2/(e^2x+1)
                float th = 1.f - 2.f / (ex + 1.f);
                s = fmaf(th, vr[in], s);
            }
            s += __shfl_xor(s, 1); s += __shfl_xor(s, 2);
            s += __shfl_xor(s, 4); s += __shfl_xor(s, 8);
            if (l15 == 0) sc[wid * 128 + im * 16 + g * 4 + r] = s;
        }
    }
    __syncthreads();
    if (tid < 256) {
        int wm = tid >> 7, lr = tid & 127;
        float s = sc[(wm * 4 + 0) * 128 + lr] + sc[(wm * 4 + 1) * 128 + lr]
                + sc[(wm * 4 + 2) * 128 + lr] + sc[(wm * 4 + 3) * 128 + lr];
        spart[(size_t)nt * (B_ * S_) + (size_t)mtile * 256 + tid] = s;
    }
}
#undef COMP
#undef WRA
#undef LDA
#undef STAGE_B
#undef GLD

// ---------------- k2 (fallback): fp32 A with inline cvt ----------------
__global__ __launch_bounds__(512, 2) void k_gemm_fb(
        const float* __restrict__ enc, const f16* __restrict__ wc16,
        const float* __restrict__ hp, const float* __restrict__ bc,
        const float* __restrict__ v, float* __restrict__ scores) {
    __shared__ f16 Als[2][64 * 128];
    const int tid = threadIdx.x;
    const int blk = blockIdx.x;
    const size_t m0 = (size_t)blk * 64;
    const int brow = blk >> 5;
    const int lane = tid & 63, wid = tid >> 6;
    const int g = lane >> 4, l15 = lane & 15;
    const int rsw = (l15 & 7) << 4;
    const int row0 = tid >> 4,         c80 = tid & 15;
    const int row1 = (512 + tid) >> 4, c81 = tid & 15;
    const int wb0 = row0 * 256 + ((c80 * 16) ^ ((row0 & 7) << 4));
    const int wb1 = row1 * 256 + ((c81 * 16) ^ ((row1 & 7) << 4));
    int boff[8];
    #pragma unroll
    for (int in = 0; in < 8; ++in)
        boff[in] = (wid * 128 + in * 16 + l15) * H_ + g * 8;
    int abase[4];
    #pragma unroll
    for (int im = 0; im < 4; ++im) abase[im] = (im * 16 + l15) * 256;
    f32x4 acc[4][8];
    #pragma unroll
    for (int im = 0; im < 4; ++im)
        #pragma unroll
        for (int in = 0; in < 8; ++in) acc[im][in] = (f32x4){0.f,0.f,0.f,0.f};
    float4 sr[2][2];
    {
        const float* s0 = enc + (m0 + row0) * H_ + c80 * 8;
        const float* s1 = enc + (m0 + row1) * H_ + c81 * 8;
        sr[0][0] = *(const float4*)s0; sr[0][1] = *(const float4*)(s0 + 4);
        sr[1][0] = *(const float4*)s1; sr[1][1] = *(const float4*)(s1 + 4);
    }
    for (int kc = 0; kc < 8; ++kc) {
        char* buf = (char*)Als[kc & 1];
        {
            f16x8 h0, h1;
            h0[0]=(f16)sr[0][0].x; h0[1]=(f16)sr[0][0].y; h0[2]=(f16)sr[0][0].z; h0[3]=(f16)sr[0][0].w;
            h0[4]=(f16)sr[0][1].x; h0[5]=(f16)sr[0][1].y; h0[6]=(f16)sr[0][1].z; h0[7]=(f16)sr[0][1].w;
            h1[0]=(f16)sr[1][0].x; h1[1]=(f16)sr[1][0].y; h1[2]=(f16)sr[1][0].z; h1[3]=(f16)sr[1][0].w;
            h1[4]=(f16)sr[1][1].x; h1[5]=(f16)sr[1][1].y; h1[6]=(f16)sr[1][1].z; h1[7]=(f16)sr[1][1].w;
            *(f16x8*)(buf + wb0) = h0;
            *(f16x8*)(buf + wb1) = h1;
        }
        __syncthreads();
        if (kc < 7) {
            const float* s0 = enc + (m0 + row0) * H_ + (kc + 1) * 128 + c80 * 8;
            const float* s1 = enc + (m0 + row1) * H_ + (kc + 1) * 128 + c81 * 8;
            sr[0][0] = *(const float4*)s0; sr[0][1] = *(const float4*)(s0 + 4);
            sr[1][0] = *(const float4*)s1; sr[1][1] = *(const float4*)(s1 + 4);
        }
        #pragma unroll
        for (int ks = 0; ks < 4; ++ks) {
            f16x8 bfv[8];
            #pragma unroll
            for (int in = 0; in < 8; ++in)
                bfv[in] = *(const f16x8*)(wc16 + boff[in] + kc * 128 + ks * 32);
            const int coff = (ks * 64 + g * 16) ^ rsw;
            f16x8 af[4];
            #pragma unroll
            for (int im = 0; im < 4; ++im)
                af[im] = *(const f16x8*)(buf + abase[im] + coff);
            #pragma unroll
            for (int im = 0; im < 4; ++im)
                #pragma unroll
                for (int in = 0; in < 8; ++in)
                    acc[im][in] = __builtin_amdgcn_mfma_f32_16x16x32_f16(
                        af[im], bfv[in], acc[im][in], 0, 0, 0);
        }
    }
    float hpbcr[8], vr[8];
    #pragma unroll
    for (int in = 0; in < 8; ++in) {
        int col = wid * 128 + in * 16 + l15;
        hpbcr[in] = hp[brow * H_ + col] + bc[col];
        vr[in]    = v[col];
    }
    float score[4][4];
    #pragma unroll
    for (int im = 0; im < 4; ++im)
        #pragma unroll
        for (int r = 0; r < 4; ++r) {
            float s = 0.f;
            #pragma unroll
            for (int in = 0; in < 8; ++in) {
                float e = acc[im][in][r] + hpbcr[in];
                float ex = __expf(2.f * e);
                float th = 1.f - 2.f / (ex + 1.f);
                s = fmaf(th, vr[in], s);
            }
            s += __shfl_xor(s, 1); s += __shfl_xor(s, 2);
            s += __shfl_xor(s, 4); s += __shfl_xor(s, 8);
            score[im][r] = s;
        }
    __syncthreads();
    float* sc = (float*)Als;
    if (l15 == 0) {
        #pragma unroll
        for (int im = 0; im < 4; ++im)
            #pragma unroll
            for (int r = 0; r < 4; ++r)
                sc[wid * 64 + im * 16 + g * 4 + r] = score[im][r];
    }
    __syncthreads();
    if (tid < 64) {
        float s = 0.f;
        #pragma unroll
        for (int w = 0; w < 8; ++w) s += sc[w * 64 + tid];
        scores[m0 + tid] = s;
    }
}

// ---------------- k3 (fast): fused 4-partial reduce + softmax ------------
__global__ void k_softmax4(const float* __restrict__ spart, float* __restrict__ attn) {
    __shared__ float red[4], red2[4];
    int b = blockIdx.x, tid = threadIdx.x, lane = tid & 63, w = tid >> 6;
    const float* sp = spart + (size_t)b * S_;
    float lv[8];
    float mx = -1e30f;
    #pragma unroll
    for (int i = 0; i < 8; ++i) {
        size_t r = (size_t)i * 256 + tid;
        lv[i] = sp[r] + sp[(size_t)(B_*S_) + r]
              + sp[2*(size_t)(B_*S_) + r] + sp[3*(size_t)(B_*S_) + r];
        mx = fmaxf(mx, lv[i]);
    }
    #pragma unroll
    for (int m = 32; m; m >>= 1) mx = fmaxf(mx, __shfl_xor(mx, m));
    if (lane == 0) red[w] = mx;
    __syncthreads();
    mx = fmaxf(fmaxf(red[0], red[1]), fmaxf(red[2], red[3]));
    float sum = 0.f;
    #pragma unroll
    for (int i = 0; i < 8; ++i) { lv[i] = expf(lv[i] - mx); sum += lv[i]; }
    #pragma unroll
    for (int m = 32; m; m >>= 1) sum += __shfl_xor(sum, m);
    if (lane == 0) red2[w] = sum;
    __syncthreads();
    sum = red2[0] + red2[1] + red2[2] + red2[3];
    float inv = 1.f / sum;
    #pragma unroll
    for (int i = 0; i < 8; ++i) attn[b * S_ + i * 256 + tid] = lv[i] * inv;
}

// ---------------- k3 (fallback): softmax over S per batch ----------------
__global__ void k_softmax(const float* __restrict__ scores, float* __restrict__ attn) {
    __shared__ float red[4], red2[4];
    int b = blockIdx.x, tid = threadIdx.x, lane = tid & 63, w = tid >> 6;
    const float* sc = scores + b * S_;
    float lv[8];
    float mx = -1e30f;
    #pragma unroll
    for (int i = 0; i < 8; ++i) { lv[i] = sc[i * 256 + tid]; mx = fmaxf(mx, lv[i]); }
    #pragma unroll
    for (int m = 32; m; m >>= 1) mx = fmaxf(mx, __shfl_xor(mx, m));
    if (lane == 0) red[w] = mx;
    __syncthreads();
    mx = fmaxf(fmaxf(red[0], red[1]), fmaxf(red[2], red[3]));
    float sum = 0.f;
    #pragma unroll
    for (int i = 0; i < 8; ++i) { lv[i] = expf(lv[i] - mx); sum += lv[i]; }
    #pragma unroll
    for (int m = 32; m; m >>= 1) sum += __shfl_xor(sum, m);
    if (lane == 0) red2[w] = sum;
    __syncthreads();
    sum = red2[0] + red2[1] + red2[2] + red2[3];
    float inv = 1.f / sum;
    #pragma unroll
    for (int i = 0; i < 8; ++i) attn[b * S_ + i * 256 + tid] = lv[i] * inv;
}

// ---------------- k4a (fast): partial context from 32KB swizzled images ----
// grid 4096 = mtile*16 + kc; 64 thr: kg = tid&7, q = tid>>3 (32 rows each)
__global__ void k_ctxpart16(const f16* __restrict__ enc16, const float* __restrict__ attn,
                            float* __restrict__ cpart) {
    int bid = blockIdx.x, mtile = bid >> 4, kc = bid & 15;
    int b = mtile >> 3;
    int tid = threadIdx.x;
    int kg = tid & 7, q = tid >> 3;
    const char* img = (const char*)enc16 + ((size_t)bid << 15);
    const float* arow = attn + b * S_ + (mtile & 7) * 256;
    float acc[8] = {0,0,0,0,0,0,0,0};
    #pragma unroll 8
    for (int rr = 0; rr < 32; ++rr) {
        int r = q * 32 + rr;
        float a = arow[r];
        f16x8 e = *(const f16x8*)(img + r * 128 + ((kg * 16) ^ ((r & 7) << 4)));
        #pragma unroll
        for (int j = 0; j < 8; ++j) acc[j] = fmaf(a, (float)e[j], acc[j]);
    }
    float* dst = cpart + (size_t)(b * 64 + (mtile & 7) * 8 + q) * H_ + kc * 64 + kg * 8;
    #pragma unroll
    for (int j = 0; j < 8; ++j) dst[j] = acc[j];
}

// ---------------- k4a (fallback): fp32 enc ----------------
__global__ void k_ctxpart(const float* __restrict__ enc, const float* __restrict__ attn,
                          float* __restrict__ cpart) {
    int b = blockIdx.x >> 5, chunk = blockIdx.x & 31;
    int t = threadIdx.x;
    const float* arow = attn + b * S_;
    f32x4 acc = {0.f, 0.f, 0.f, 0.f};
    for (int s0 = 0; s0 < 64; ++s0) {
        int s = chunk * 64 + s0;
        float a = arow[s];
        float4 e = *(const float4*)(enc + ((size_t)b * S_ + s) * H_ + t * 4);
        acc[0] += a * e.x; acc[1] += a * e.y; acc[2] += a * e.z; acc[3] += a * e.w;
    }
    *(f32x4*)(cpart + (size_t)blockIdx.x * H_ + t * 4) = acc;
}

// ---------------- k4b: reduce chunks -> context ----------------
__global__ void k_ctxreduce(const float* __restrict__ cpart, float* __restrict__ ctx, int nc) {
    int idx = blockIdx.x * 256 + threadIdx.x;
    int b = idx >> 10, h = idx & 1023;
    float s = 0.f;
    for (int c = 0; c < nc; ++c) s += cpart[((size_t)(b * nc + c)) * H_ + h];
    ctx[idx] = s;
}

extern "C" void kernel_launch(void* const* d_in, const int* in_sizes, int n_in,
                              void* d_out, int out_size, void* d_ws, size_t ws_size,
                              hipStream_t stream) {
    const float* hidden = (const float*)d_in[0];
    const float* enc    = (const float*)d_in[1];
    const float* Wh     = (const float*)d_in[2];
    const float* bh     = (const float*)d_in[3];
    const float* Wc     = (const float*)d_in[4];
    const float* bc     = (const float*)d_in[5];
    const float* v      = (const float*)d_in[6];
    float* out = (float*)d_out;
    (void)in_sizes; (void)n_in; (void)out_size;

    char* ws = (char*)d_ws;
    f16*   wc16   = (f16*)ws;                                  // 2 MB
    float* hp     = (float*)(ws + (2u << 20));                 // 128 KB
    float* scores = (float*)(ws + (2u << 20) + (128u << 10));  // 256 KB
    float* spart  = (float*)(ws + (2u << 20) + (384u << 10));  // 1 MB
    float* cpart  = (float*)(ws + (4u << 20));                 // 8 MB
    f16*   enc16  = (f16*)(ws + (16u << 20));                  // 128 MB (fast only)

    const size_t need_fast = (size_t)(16u << 20) + ((size_t)128 << 20);
    const bool fast = ws_size >= need_fast;

    float* attn = out + B_ * H_;   // d_out: context [32,1024], attn [32,2048]

    hipLaunchKernelGGL(k_hp,      dim3(8192), dim3(256), 0, stream, hidden, Wh, bh, hp);
    if (fast) {
        hipLaunchKernelGGL(k_cvt_img,  dim3(64),   dim3(256), 0, stream, Wc, wc16);
        hipLaunchKernelGGL(k_gemm,     dim3(1024), dim3(512), 0, stream, enc, wc16, enc16, hp, bc, v, spart);
        hipLaunchKernelGGL(k_softmax4, dim3(32),   dim3(256), 0, stream, spart, attn);
        hipLaunchKernelGGL(k_ctxpart16,dim3(4096), dim3(64),  0, stream, enc16, attn, cpart);
        hipLaunchKernelGGL(k_ctxreduce,dim3(128),  dim3(256), 0, stream, cpart, out, 64);
    } else {
        hipLaunchKernelGGL(k_cvt_wc,   dim3(1024), dim3(256), 0, stream, Wc, wc16);
        hipLaunchKernelGGL(k_gemm_fb,  dim3(1024), dim3(512), 0, stream, enc, wc16, hp, bc, v, scores);
        hipLaunchKernelGGL(k_softmax,  dim3(32),   dim3(256), 0, stream, scores, attn);
        hipLaunchKernelGGL(k_ctxpart,  dim3(1024), dim3(256), 0, stream, enc, attn, cpart);
        hipLaunchKernelGGL(k_ctxreduce,dim3(128),  dim3(256), 0, stream, cpart, out, 32);
    }
}

// Round 10
// 260.337 us; speedup vs baseline: 1.8216x; 1.8216x over previous
//
#include <hip/hip_runtime.h>
#include <hip/hip_fp16.h>
#include <math.h>
#include <stdint.h>

#define B_ 32
#define S_ 2048
#define H_ 1024

typedef _Float16 f16;
typedef _Float16 f16x8 __attribute__((ext_vector_type(8)));
typedef _Float16 f16x4 __attribute__((ext_vector_type(4)));
typedef float    f32x4 __attribute__((ext_vector_type(4)));

// ---------------- k0: W_c fp32 -> fp16 row-major (fallback only) ----------
__global__ void k_cvt_wc(const float* __restrict__ wc, f16* __restrict__ wc16) {
    int i = (blockIdx.x * 256 + threadIdx.x) * 4;
    float4 vv = *(const float4*)(wc + i);
    f16x4 h;
    h[0] = (f16)vv.x; h[1] = (f16)vv.y; h[2] = (f16)vv.z; h[3] = (f16)vv.w;
    *(f16x4*)(wc16 + i) = h;
}

// ---------------- k0b: fp32 -> fp16 pre-swizzled 32KB images --------------
// image (rt, kc 0..15): rows r=0..255 (128B/row), k=0..63.
// byte(r,k) = r*128 + (((k>>3)*16) ^ ((r&7)<<4)) + (k&7)*2
// Fast path: used for Wc only (rt 0..3, grid 64).
__global__ void k_cvt_img(const float* __restrict__ src, f16* __restrict__ dst) {
    int bid = blockIdx.x;                 // rt*16 + kc
    int rt = bid >> 4, kc = bid & 15;
    int tid = threadIdx.x;
    char* img = (char*)dst + ((size_t)bid << 15);
    #pragma unroll
    for (int i = 0; i < 8; ++i) {
        int gid = i * 256 + tid;          // 0..2047
        int r = gid >> 3, kg = gid & 7;
        const float* s = src + ((size_t)(rt * 256 + r)) * H_ + kc * 64 + kg * 8;
        float4 lo = *(const float4*)s;
        float4 hi = *(const float4*)(s + 4);
        f16x8 h;
        h[0]=(f16)lo.x; h[1]=(f16)lo.y; h[2]=(f16)lo.z; h[3]=(f16)lo.w;
        h[4]=(f16)hi.x; h[5]=(f16)hi.y; h[6]=(f16)hi.z; h[7]=(f16)hi.w;
        int byte = r * 128 + ((kg * 16) ^ ((r & 7) << 4));
        *(f16x8*)(img + byte) = h;
    }
}

// ---------------- k1: hidden_proj = hidden @ W_h.T + b_h ----------------
__global__ void k_hp(const float* __restrict__ hid, const float* __restrict__ Wh,
                     const float* __restrict__ bh, float* __restrict__ hp) {
    int wid  = (blockIdx.x * 256 + threadIdx.x) >> 6;
    int lane = threadIdx.x & 63;
    int b = wid >> 10, oo = wid & 1023;
    const float* hrow = hid + b * H_;
    const float* wrow = Wh + (size_t)oo * H_;
    float s = 0.f;
    #pragma unroll
    for (int i = 0; i < 16; ++i) {
        int k = i * 64 + lane;
        s += hrow[k] * wrow[k];
    }
    #pragma unroll
    for (int m = 32; m; m >>= 1) s += __shfl_xor(s, m);
    if (lane == 0) hp[wid] = s + bh[oo];
}

// ---------------- k2: 256x256 tile, fused fp32-A cvt (single reg set) -----
// r5 structure (one syncthreads/tile, 24 ds_read + 64 MFMA) but A comes from
// fp32 enc: ONE set of 8 float4 (32 VGPR) reg-staged per tile, issued a full
// COMP early (T14), cvt to f16 (RTE, bit-identical), ds_write the swizzled
// image bytes. NO enc16 side-write (ctxpart reads fp32). Eliminates the
// 61 us enc cvt pass + 1 launch. B still gload_lds from wc16 images.
#define GLD(dst_, src_) __builtin_amdgcn_global_load_lds(                      \
    (const __attribute__((address_space(1))) uint32_t*)(src_),                 \
    (__attribute__((address_space(3))) uint32_t*)(dst_), 16, 0, 0)

#define STAGE_B(t_) do {                                                       \
    _Pragma("unroll")                                                          \
    for (int i_ = 0; i_ < 4; ++i_) {                                           \
        int off_ = (i_ * 512 + tid) * 16;                                      \
        GLD(&Als[(t_) & 1][32768 + off_], bimg + ((size_t)(t_) << 15) + off_); \
    }                                                                          \
} while (0)

// load fp32 A for tile t_ into the single register set sA
#define LDA(t_) do {                                                           \
    _Pragma("unroll")                                                          \
    for (int i_ = 0; i_ < 4; ++i_) {                                           \
        const float* s_ = asrc + (size_t)(i_ * 64) * H_ + (t_) * 64;           \
        sA[i_][0] = *(const float4*)s_;                                        \
        sA[i_][1] = *(const float4*)(s_ + 4);                                  \
    }                                                                          \
} while (0)

// cvt sA -> f16 image bytes; write LDS A-region of buf[t_&1]
#define WRA(t_) do {                                                           \
    _Pragma("unroll")                                                          \
    for (int i_ = 0; i_ < 4; ++i_) {                                           \
        f16x8 h_;                                                              \
        h_[0]=(f16)sA[i_][0].x; h_[1]=(f16)sA[i_][0].y;                        \
        h_[2]=(f16)sA[i_][0].z; h_[3]=(f16)sA[i_][0].w;                        \
        h_[4]=(f16)sA[i_][1].x; h_[5]=(f16)sA[i_][1].y;                        \
        h_[6]=(f16)sA[i_][1].z; h_[7]=(f16)sA[i_][1].w;                        \
        int off_ = (i_ * 512 + tid) * 16;                                      \
        *(f16x8*)(&Als[(t_) & 1][off_]) = h_;                                  \
    }                                                                          \
} while (0)

#define COMP(kc_) do {                                                         \
    const char* buf_ = Als[(kc_) & 1];                                         \
    _Pragma("unroll")                                                          \
    for (int ks_ = 0; ks_ < 2; ++ks_) {                                        \
        const int coff_ = (ks_ * 64 + g * 16) ^ rsw;                           \
        f16x8 bfv_[4];                                                         \
        _Pragma("unroll")                                                      \
        for (int in_ = 0; in_ < 4; ++in_)                                      \
            bfv_[in_] = *(const f16x8*)(buf_ + 32768 + bbase[in_] + coff_);    \
        f16x8 af_[8];                                                          \
        _Pragma("unroll")                                                      \
        for (int im_ = 0; im_ < 8; ++im_)                                      \
            af_[im_] = *(const f16x8*)(buf_ + abase[im_] + coff_);             \
        _Pragma("unroll")                                                      \
        for (int im_ = 0; im_ < 8; ++im_)                                      \
            _Pragma("unroll")                                                  \
            for (int in_ = 0; in_ < 4; ++in_)                                  \
                acc[im_][in_] = __builtin_amdgcn_mfma_f32_16x16x32_f16(        \
                    af_[im_], bfv_[in_], acc[im_][in_], 0, 0, 0);              \
    }                                                                          \
} while (0)

__global__ __launch_bounds__(512, 2) void k_gemm(
        const float* __restrict__ enc, const f16* __restrict__ wc16,
        const float* __restrict__ hp, const float* __restrict__ bc,
        const float* __restrict__ v, float* __restrict__ spart) {
    __shared__ __align__(16) char Als[2][65536];   // 128 KB

    const int tid = threadIdx.x;
    const int hb  = blockIdx.x;
    const int o   = (hb & 7) * 128 + (hb >> 3);    // bijective XCD swizzle
    const int mtile = o >> 2, nt = o & 3;          // 256-row / 256-col tiles
    const int brow = mtile >> 3;                   // batch
    const int lane = tid & 63, wid = tid >> 6;     // wid 0..7
    const int waveM = wid >> 2, waveN = wid & 3;
    const int g = lane >> 4, l15 = lane & 15;
    const int rsw = (l15 & 7) << 4;

    // fp32 A staging decomposition: image 16B-slot idx16 = i*512 + tid
    //   r = i*64 + (tid>>3), kg = (tid&7) ^ (r&7)
    const int srow = tid >> 3;
    const int skg  = (tid & 7) ^ (srow & 7);
    const float* asrc = enc + ((size_t)mtile * 256 + srow) * H_ + skg * 8;
    const char* bimg = (const char*)wc16 + ((size_t)nt << 19);      // 16x32KB

    // A frag row base bytes: row = waveM*128 + im*16 + l15 (128 B rows)
    int abase[8];
    #pragma unroll
    for (int im = 0; im < 8; ++im)
        abase[im] = (waveM * 128 + im * 16 + l15) * 128;
    // B frag base bytes (within B region): col = waveN*64 + in*16 + l15
    int bbase[4];
    #pragma unroll
    for (int in = 0; in < 4; ++in)
        bbase[in] = (waveN * 64 + in * 16 + l15) * 128;

    f32x4 acc[8][4];
    #pragma unroll
    for (int im = 0; im < 8; ++im)
        #pragma unroll
        for (int in = 0; in < 4; ++in) acc[im][in] = (f32x4){0.f, 0.f, 0.f, 0.f};

    float4 sA[4][2];               // single fp32 A staging set (32 VGPR)

    // prologue: A(0) load+write, B(0) staged, A(1) loads in flight
    LDA(0);
    STAGE_B(0);
    WRA(0);
    LDA(1);

    #pragma unroll 1
    for (int kc = 0; kc < 16; ++kc) {
        __syncthreads();           // buf[kc] ready (A written, B landed); buf[kc^1] free
        if (kc < 15) { WRA(kc + 1); STAGE_B(kc + 1); }  // WRA consumes LDA(kc+1)
        if (kc < 14) LDA(kc + 2);  // reuse set; full COMP of slack before use
        COMP(kc);
    }

    // epilogue: partial score over this ntile's 256 cols
    float hpbcr[4], vr[4];
    #pragma unroll
    for (int in = 0; in < 4; ++in) {
        int col = nt * 256 + waveN * 64 + in * 16 + l15;
        hpbcr[in] = hp[brow * H_ + col] + bc[col];
        vr[in]    = v[col];
    }
    float* sc = (float*)Als;          // overlay Als[0]; tile 15 read Als[1]
    #pragma unroll
    for (int im = 0; im < 8; ++im) {
        #pragma unroll
        for (int r = 0; r < 4; ++r) {
            float s = 0.f;
            #pragma unroll
            for (int in = 0; in < 4; ++in) {
                float e = acc[im][in][r] + hpbcr[in];
                float ex = __expf(2.f * e);       // tanh = 1 - 2/(e^2x+1)
                float th = 1.f - 2.f / (ex + 1.f);
                s = fmaf(th, vr[in], s);
            }
            s += __shfl_xor(s, 1); s += __shfl_xor(s, 2);
            s += __shfl_xor(s, 4); s += __shfl_xor(s, 8);
            if (l15 == 0) sc[wid * 128 + im * 16 + g * 4 + r] = s;
        }
    }
    __syncthreads();
    if (tid < 256) {
        int wm = tid >> 7, lr = tid & 127;
        float s = sc[(wm * 4 + 0) * 128 + lr] + sc[(wm * 4 + 1) * 128 + lr]
                + sc[(wm * 4 + 2) * 128 + lr] + sc[(wm * 4 + 3) * 128 + lr];
        spart[(size_t)nt * (B_ * S_) + (size_t)mtile * 256 + tid] = s;
    }
}
#undef COMP
#undef WRA
#undef LDA
#undef STAGE_B
#undef GLD

// ---------------- k2 (fallback): fp32 A with inline cvt ----------------
__global__ __launch_bounds__(512, 2) void k_gemm_fb(
        const float* __restrict__ enc, const f16* __restrict__ wc16,
        const float* __restrict__ hp, const float* __restrict__ bc,
        const float* __restrict__ v, float* __restrict__ scores) {
    __shared__ f16 Als[2][64 * 128];
    const int tid = threadIdx.x;
    const int blk = blockIdx.x;
    const size_t m0 = (size_t)blk * 64;
    const int brow = blk >> 5;
    const int lane = tid & 63, wid = tid >> 6;
    const int g = lane >> 4, l15 = lane & 15;
    const int rsw = (l15 & 7) << 4;
    const int row0 = tid >> 4,         c80 = tid & 15;
    const int row1 = (512 + tid) >> 4, c81 = tid & 15;
    const int wb0 = row0 * 256 + ((c80 * 16) ^ ((row0 & 7) << 4));
    const int wb1 = row1 * 256 + ((c81 * 16) ^ ((row1 & 7) << 4));
    int boff[8];
    #pragma unroll
    for (int in = 0; in < 8; ++in)
        boff[in] = (wid * 128 + in * 16 + l15) * H_ + g * 8;
    int abase[4];
    #pragma unroll
    for (int im = 0; im < 4; ++im) abase[im] = (im * 16 + l15) * 256;
    f32x4 acc[4][8];
    #pragma unroll
    for (int im = 0; im < 4; ++im)
        #pragma unroll
        for (int in = 0; in < 8; ++in) acc[im][in] = (f32x4){0.f,0.f,0.f,0.f};
    float4 sr[2][2];
    {
        const float* s0 = enc + (m0 + row0) * H_ + c80 * 8;
        const float* s1 = enc + (m0 + row1) * H_ + c81 * 8;
        sr[0][0] = *(const float4*)s0; sr[0][1] = *(const float4*)(s0 + 4);
        sr[1][0] = *(const float4*)s1; sr[1][1] = *(const float4*)(s1 + 4);
    }
    for (int kc = 0; kc < 8; ++kc) {
        char* buf = (char*)Als[kc & 1];
        {
            f16x8 h0, h1;
            h0[0]=(f16)sr[0][0].x; h0[1]=(f16)sr[0][0].y; h0[2]=(f16)sr[0][0].z; h0[3]=(f16)sr[0][0].w;
            h0[4]=(f16)sr[0][1].x; h0[5]=(f16)sr[0][1].y; h0[6]=(f16)sr[0][1].z; h0[7]=(f16)sr[0][1].w;
            h1[0]=(f16)sr[1][0].x; h1[1]=(f16)sr[1][0].y; h1[2]=(f16)sr[1][0].z; h1[3]=(f16)sr[1][0].w;
            h1[4]=(f16)sr[1][1].x; h1[5]=(f16)sr[1][1].y; h1[6]=(f16)sr[1][1].z; h1[7]=(f16)sr[1][1].w;
            *(f16x8*)(buf + wb0) = h0;
            *(f16x8*)(buf + wb1) = h1;
        }
        __syncthreads();
        if (kc < 7) {
            const float* s0 = enc + (m0 + row0) * H_ + (kc + 1) * 128 + c80 * 8;
            const float* s1 = enc + (m0 + row1) * H_ + (kc + 1) * 128 + c81 * 8;
            sr[0][0] = *(const float4*)s0; sr[0][1] = *(const float4*)(s0 + 4);
            sr[1][0] = *(const float4*)s1; sr[1][1] = *(const float4*)(s1 + 4);
        }
        #pragma unroll
        for (int ks = 0; ks < 4; ++ks) {
            f16x8 bfv[8];
            #pragma unroll
            for (int in = 0; in < 8; ++in)
                bfv[in] = *(const f16x8*)(wc16 + boff[in] + kc * 128 + ks * 32);
            const int coff = (ks * 64 + g * 16) ^ rsw;
            f16x8 af[4];
            #pragma unroll
            for (int im = 0; im < 4; ++im)
                af[im] = *(const f16x8*)(buf + abase[im] + coff);
            #pragma unroll
            for (int im = 0; im < 4; ++im)
                #pragma unroll
                for (int in = 0; in < 8; ++in)
                    acc[im][in] = __builtin_amdgcn_mfma_f32_16x16x32_f16(
                        af[im], bfv[in], acc[im][in], 0, 0, 0);
        }
    }
    float hpbcr[8], vr[8];
    #pragma unroll
    for (int in = 0; in < 8; ++in) {
        int col = wid * 128 + in * 16 + l15;
        hpbcr[in] = hp[brow * H_ + col] + bc[col];
        vr[in]    = v[col];
    }
    float score[4][4];
    #pragma unroll
    for (int im = 0; im < 4; ++im)
        #pragma unroll
        for (int r = 0; r < 4; ++r) {
            float s = 0.f;
            #pragma unroll
            for (int in = 0; in < 8; ++in) {
                float e = acc[im][in][r] + hpbcr[in];
                float ex = __expf(2.f * e);
                float th = 1.f - 2.f / (ex + 1.f);
                s = fmaf(th, vr[in], s);
            }
            s += __shfl_xor(s, 1); s += __shfl_xor(s, 2);
            s += __shfl_xor(s, 4); s += __shfl_xor(s, 8);
            score[im][r] = s;
        }
    __syncthreads();
    float* sc = (float*)Als;
    if (l15 == 0) {
        #pragma unroll
        for (int im = 0; im < 4; ++im)
            #pragma unroll
            for (int r = 0; r < 4; ++r)
                sc[wid * 64 + im * 16 + g * 4 + r] = score[im][r];
    }
    __syncthreads();
    if (tid < 64) {
        float s = 0.f;
        #pragma unroll
        for (int w = 0; w < 8; ++w) s += sc[w * 64 + tid];
        scores[m0 + tid] = s;
    }
}

// ---------------- k3 (fast): fused 4-partial reduce + softmax ------------
__global__ void k_softmax4(const float* __restrict__ spart, float* __restrict__ attn) {
    __shared__ float red[4], red2[4];
    int b = blockIdx.x, tid = threadIdx.x, lane = tid & 63, w = tid >> 6;
    const float* sp = spart + (size_t)b * S_;
    float lv[8];
    float mx = -1e30f;
    #pragma unroll
    for (int i = 0; i < 8; ++i) {
        size_t r = (size_t)i * 256 + tid;
        lv[i] = sp[r] + sp[(size_t)(B_*S_) + r]
              + sp[2*(size_t)(B_*S_) + r] + sp[3*(size_t)(B_*S_) + r];
        mx = fmaxf(mx, lv[i]);
    }
    #pragma unroll
    for (int m = 32; m; m >>= 1) mx = fmaxf(mx, __shfl_xor(mx, m));
    if (lane == 0) red[w] = mx;
    __syncthreads();
    mx = fmaxf(fmaxf(red[0], red[1]), fmaxf(red[2], red[3]));
    float sum = 0.f;
    #pragma unroll
    for (int i = 0; i < 8; ++i) { lv[i] = expf(lv[i] - mx); sum += lv[i]; }
    #pragma unroll
    for (int m = 32; m; m >>= 1) sum += __shfl_xor(sum, m);
    if (lane == 0) red2[w] = sum;
    __syncthreads();
    sum = red2[0] + red2[1] + red2[2] + red2[3];
    float inv = 1.f / sum;
    #pragma unroll
    for (int i = 0; i < 8; ++i) attn[b * S_ + i * 256 + tid] = lv[i] * inv;
}

// ---------------- k3 (fallback): softmax over S per batch ----------------
__global__ void k_softmax(const float* __restrict__ scores, float* __restrict__ attn) {
    __shared__ float red[4], red2[4];
    int b = blockIdx.x, tid = threadIdx.x, lane = tid & 63, w = tid >> 6;
    const float* sc = scores + b * S_;
    float lv[8];
    float mx = -1e30f;
    #pragma unroll
    for (int i = 0; i < 8; ++i) { lv[i] = sc[i * 256 + tid]; mx = fmaxf(mx, lv[i]); }
    #pragma unroll
    for (int m = 32; m; m >>= 1) mx = fmaxf(mx, __shfl_xor(mx, m));
    if (lane == 0) red[w] = mx;
    __syncthreads();
    mx = fmaxf(fmaxf(red[0], red[1]), fmaxf(red[2], red[3]));
    float sum = 0.f;
    #pragma unroll
    for (int i = 0; i < 8; ++i) { lv[i] = expf(lv[i] - mx); sum += lv[i]; }
    #pragma unroll
    for (int m = 32; m; m >>= 1) sum += __shfl_xor(sum, m);
    if (lane == 0) red2[w] = sum;
    __syncthreads();
    sum = red2[0] + red2[1] + red2[2] + red2[3];
    float inv = 1.f / sum;
    #pragma unroll
    for (int i = 0; i < 8; ++i) attn[b * S_ + i * 256 + tid] = lv[i] * inv;
}

// ---------------- k4a: partial context from fp32 enc ----------------
__global__ void k_ctxpart(const float* __restrict__ enc, const float* __restrict__ attn,
                          float* __restrict__ cpart) {
    int b = blockIdx.x >> 5, chunk = blockIdx.x & 31;
    int t = threadIdx.x;
    const float* arow = attn + b * S_;
    f32x4 acc = {0.f, 0.f, 0.f, 0.f};
    for (int s0 = 0; s0 < 64; ++s0) {
        int s = chunk * 64 + s0;
        float a = arow[s];
        float4 e = *(const float4*)(enc + ((size_t)b * S_ + s) * H_ + t * 4);
        acc[0] += a * e.x; acc[1] += a * e.y; acc[2] += a * e.z; acc[3] += a * e.w;
    }
    *(f32x4*)(cpart + (size_t)blockIdx.x * H_ + t * 4) = acc;
}

// ---------------- k4b: reduce chunks -> context ----------------
__global__ void k_ctxreduce(const float* __restrict__ cpart, float* __restrict__ ctx, int nc) {
    int idx = blockIdx.x * 256 + threadIdx.x;
    int b = idx >> 10, h = idx & 1023;
    float s = 0.f;
    for (int c = 0; c < nc; ++c) s += cpart[((size_t)(b * nc + c)) * H_ + h];
    ctx[idx] = s;
}

extern "C" void kernel_launch(void* const* d_in, const int* in_sizes, int n_in,
                              void* d_out, int out_size, void* d_ws, size_t ws_size,
                              hipStream_t stream) {
    const float* hidden = (const float*)d_in[0];
    const float* enc    = (const float*)d_in[1];
    const float* Wh     = (const float*)d_in[2];
    const float* bh     = (const float*)d_in[3];
    const float* Wc     = (const float*)d_in[4];
    const float* bc     = (const float*)d_in[5];
    const float* v      = (const float*)d_in[6];
    float* out = (float*)d_out;
    (void)in_sizes; (void)n_in; (void)out_size;

    char* ws = (char*)d_ws;
    f16*   wc16   = (f16*)ws;                                  // 2 MB
    float* hp     = (float*)(ws + (2u << 20));                 // 128 KB
    float* scores = (float*)(ws + (2u << 20) + (128u << 10));  // 256 KB
    float* spart  = (float*)(ws + (2u << 20) + (384u << 10));  // 1 MB
    float* cpart  = (float*)(ws + (4u << 20));                 // 8 MB

    const bool fast = ws_size >= (size_t)(16u << 20);

    float* attn = out + B_ * H_;   // d_out: context [32,1024], attn [32,2048]

    hipLaunchKernelGGL(k_hp,      dim3(8192), dim3(256), 0, stream, hidden, Wh, bh, hp);
    if (fast) {
        hipLaunchKernelGGL(k_cvt_img,  dim3(64),   dim3(256), 0, stream, Wc, wc16);
        hipLaunchKernelGGL(k_gemm,     dim3(1024), dim3(512), 0, stream, enc, wc16, hp, bc, v, spart);
        hipLaunchKernelGGL(k_softmax4, dim3(32),   dim3(256), 0, stream, spart, attn);
        hipLaunchKernelGGL(k_ctxpart,  dim3(1024), dim3(256), 0, stream, enc, attn, cpart);
        hipLaunchKernelGGL(k_ctxreduce,dim3(128),  dim3(256), 0, stream, cpart, out, 32);
    } else {
        hipLaunchKernelGGL(k_cvt_wc,   dim3(1024), dim3(256), 0, stream, Wc, wc16);
        hipLaunchKernelGGL(k_gemm_fb,  dim3(1024), dim3(512), 0, stream, enc, wc16, hp, bc, v, scores);
        hipLaunchKernelGGL(k_softmax,  dim3(32),   dim3(256), 0, stream, scores, attn);
        hipLaunchKernelGGL(k_ctxpart,  dim3(1024), dim3(256), 0, stream, enc, attn, cpart);
        hipLaunchKernelGGL(k_ctxreduce,dim3(128),  dim3(256), 0, stream, cpart, out, 32);
    }
}